// Round 9
// baseline (83.303 us; speedup 1.0000x reference)
//
#include <hip/hip_runtime.h>

// ReflexPolicy fused v9 = v5 compute verbatim + At staged via global_load_lds DMA
// issued BEFORE compute (latency hides under chunk compute; barrier vmcnt drain
// guarantees completion). W keeps v5's register staging path.

#define TOBS 64
#define TACT 32
#define TLAT 25
#define TB   8192
#define BT   16
#define NCH  16         // chunks of 4 o's
#define ATS  28         // At stride words (25 data + 3 pad) -> 128*28 = 3584 words/buf
#define WTS  20         // W stride words (16 data + 4 pad)
#define HSTR 68
#define NDMA 14         // At DMA slots per wave (56 total, 64 words each)

#define DPP_ADD(x, ctrl) \
  ((x) + __builtin_bit_cast(float, __builtin_amdgcn_update_dpp( \
      0, __builtin_bit_cast(int, (x)), (ctrl), 0xF, 0xF, true)))

__device__ __forceinline__ float halfwave_sum(float x) {
    x = DPP_ADD(x, 0xB1);   // xor1
    x = DPP_ADD(x, 0x4E);   // xor2
    x = DPP_ADD(x, 0x141);  // row_half_mirror == xor4
    x = DPP_ADD(x, 0x140);  // row_mirror      == xor8
    int y = __builtin_amdgcn_ds_swizzle(__builtin_bit_cast(int, x), 0x401F); // xor16
    return x + __builtin_bit_cast(float, y);
}

__device__ __forceinline__ float sigmoidf_(float x) {
    return 1.0f / (1.0f + __expf(-x));
}

typedef __attribute__((address_space(1))) const void* gptr_t;
typedef __attribute__((address_space(3))) void*       lptr_t;

__global__ __launch_bounds__(256, 2)
void reflex_fused(const float* __restrict__ obs,
                  const float* __restrict__ sw1, const float* __restrict__ sb1,
                  const float* __restrict__ sw2, const float* __restrict__ sb2,
                  const float* __restrict__ sw3, const float* __restrict__ sb3,
                  const float* __restrict__ rw1, const float* __restrict__ rb1,
                  const float* __restrict__ rw2, const float* __restrict__ rb2,
                  const float* __restrict__ am,  float* __restrict__ out)
{
    __shared__ __align__(16) float obs_s[BT * HSTR];
    __shared__ __align__(16) float lat_s[BT * 26];
    __shared__ __align__(16) union {
        struct { float h1[BT * HSTR]; float h2[BT * HSTR]; } p1;
        struct { float At[2][128 * ATS]; float W[2][128 * WTS]; } p2;
    } U;

    const int tid  = threadIdx.x;
    const int row0 = blockIdx.x * BT;

    // ---------------- Phase 1: supervisor (weights from L2) ----------------
    {
        const int r = tid >> 4, f = tid & 15;
        *(float4*)&obs_s[r * HSTR + f * 4] =
            *(const float4*)&obs[(row0 + r) * TOBS + f * 4];
    }
    __syncthreads();

    {   // layer 1
        const int r = tid >> 4, j0 = (tid & 15) * 4;
        float4 acc = *(const float4*)&sb1[j0];
        #pragma unroll 8
        for (int k = 0; k < 64; ++k) {
            float x = obs_s[r * HSTR + k];
            const float4 w = *(const float4*)&sw1[k * 64 + j0];
            acc.x = fmaf(x, w.x, acc.x); acc.y = fmaf(x, w.y, acc.y);
            acc.z = fmaf(x, w.z, acc.z); acc.w = fmaf(x, w.w, acc.w);
        }
        *(float4*)&U.p1.h1[r * HSTR + j0] =
            make_float4(fmaxf(acc.x, 0.f), fmaxf(acc.y, 0.f),
                        fmaxf(acc.z, 0.f), fmaxf(acc.w, 0.f));
    }
    __syncthreads();

    {   // layer 2
        const int r = tid >> 4, j0 = (tid & 15) * 4;
        float4 acc = *(const float4*)&sb2[j0];
        #pragma unroll 8
        for (int k = 0; k < 64; ++k) {
            float x = U.p1.h1[r * HSTR + k];
            const float4 w = *(const float4*)&sw2[k * 64 + j0];
            acc.x = fmaf(x, w.x, acc.x); acc.y = fmaf(x, w.y, acc.y);
            acc.z = fmaf(x, w.z, acc.z); acc.w = fmaf(x, w.w, acc.w);
        }
        *(float4*)&U.p1.h2[r * HSTR + j0] =
            make_float4(fmaxf(acc.x, 0.f), fmaxf(acc.y, 0.f),
                        fmaxf(acc.z, 0.f), fmaxf(acc.w, 0.f));
    }
    __syncthreads();

    {   // layer 3 -> lat_s
        const int r = tid >> 4, q = tid & 15;
        if (q < 13) {
            const int j = q * 2;
            float a0 = sb3[j];
            float a1 = (j + 1 < TLAT) ? sb3[j + 1] : 0.f;
            #pragma unroll 8
            for (int k = 0; k < 64; ++k) {
                float x = U.p1.h2[r * HSTR + k];
                a0 = fmaf(x, sw3[k * TLAT + j], a0);
                if (j + 1 < TLAT) a1 = fmaf(x, sw3[k * TLAT + j + 1], a1);
            }
            lat_s[r * 26 + j] = sigmoidf_(a0);
            if (j + 1 < TLAT) lat_s[r * 26 + j + 1] = sigmoidf_(a1);
        }
    }
    __syncthreads();   // lat_s ready; h1/h2 (union) dead after this point

    // ---------------- Phase 2 ----------------
    const int a    = tid & 31;
    const int hw   = tid >> 5;
    const int r0   = hw * 2, r1 = r0 + 1;
    const int wid  = tid >> 6;
    const int lane = tid & 63;

    float latA[TLAT], latB[TLAT];
    #pragma unroll
    for (int l = 0; l < TLAT; ++l) {
        latA[l] = lat_s[r0 * 26 + l];
        latB[l] = lat_s[r1 * 26 + l];
    }

    // --- At DMA setup: 56 slots x 64 words; wave w owns slots [w*14, w*14+14).
    // Buffer word p maps to (row = p/28, l = p%28); row = o_slot*32 + act.
    // Source element: am[l*2048 + (c*4 + o_slot)*32 + act]; chunk step = +128.
    int atoff[NDMA];
    #pragma unroll
    for (int k = 0; k < NDMA; ++k) {
        int p   = (wid * NDMA + k) * 64 + lane;
        int row = p / ATS;
        int l   = p - row * ATS;
        if (l > 24) l = 24;                 // pad words load a duplicate (unread)
        atoff[k] = l * 2048 + (row >> 5) * 32 + (row & 31);
    }

    auto stage_dma = [&](int b) {          // issue At DMA for current atoff state
        float* lbase = U.p2.At[b];
        #pragma unroll
        for (int k = 0; k < NDMA; ++k) {
            __builtin_amdgcn_global_load_lds(
                (gptr_t)(am + atoff[k]),
                (lptr_t)(lbase + (wid * NDMA + k) * 64),
                4, 0, 0);
            atoff[k] += 128;                // next chunk: o advances by 4
        }
    };

    // W staging: v5's register path, threads 128..255 only.
    auto stage_w = [&](int c, int b) {
        if (tid >= 128) {
            const int t = tid - 128;
            const int slot = t >> 5, a_ = t & 31;
            const int o = c * 4 + slot;
            const int gb = (o * TACT + a_) * 5;
            float w10 = rw1[gb], w11 = rw1[gb+1], w12 = rw1[gb+2], w13 = rw1[gb+3], w14 = rw1[gb+4];
            float b10 = rb1[gb], b11 = rb1[gb+1], b12 = rb1[gb+2], b13 = rb1[gb+3], b14 = rb1[gb+4];
            float w20 = rw2[gb], w21 = rw2[gb+1], w22 = rw2[gb+2], w23 = rw2[gb+3], w24 = rw2[gb+4];
            float b2v = rb2[o * TACT + a_];
            float* d = &U.p2.W[b][t * WTS];
            ((float4*)d)[0] = make_float4(w10, w11, w12, w13);
            ((float4*)d)[1] = make_float4(w14, b10, b11, b12);
            ((float4*)d)[2] = make_float4(b13, b14, w20, w21);
            ((float4*)d)[3] = make_float4(w22, w23, w24, b2v);
        }
    };

    float acc0 = 0.f, acc1 = 0.f;

    stage_dma(0);
    stage_w(0, 0);
    asm volatile("s_waitcnt vmcnt(0)" ::: "memory");
    __syncthreads();

    for (int c = 0; c < NCH; ++c) {
        if (c + 1 < NCH) stage_dma((c + 1) & 1);   // issue-early: hides under compute

        const float* Atb = U.p2.At[c & 1];
        const float* Wb  = U.p2.W[c & 1];
        #pragma unroll
        for (int i = 0; i < 4; ++i) {
            const int o  = c * 4 + i;
            const float* Ap = &Atb[(i * 32 + a) * ATS];
            const float4 A0 = ((const float4*)Ap)[0];
            const float4 A1 = ((const float4*)Ap)[1];
            const float4 A2 = ((const float4*)Ap)[2];
            const float4 A3 = ((const float4*)Ap)[3];
            const float4 A4 = ((const float4*)Ap)[4];
            const float4 A5 = ((const float4*)Ap)[5];
            const float  a24 = Ap[24];

            float l0 = 0.f, l1 = 0.f;
            #define DOT_(comp, idx) \
                l0 = fmaf((comp), latA[idx], l0); l1 = fmaf((comp), latB[idx], l1);
            DOT_(A0.x, 0)  DOT_(A0.y, 1)  DOT_(A0.z, 2)  DOT_(A0.w, 3)
            DOT_(A1.x, 4)  DOT_(A1.y, 5)  DOT_(A1.z, 6)  DOT_(A1.w, 7)
            DOT_(A2.x, 8)  DOT_(A2.y, 9)  DOT_(A2.z, 10) DOT_(A2.w, 11)
            DOT_(A3.x, 12) DOT_(A3.y, 13) DOT_(A3.z, 14) DOT_(A3.w, 15)
            DOT_(A4.x, 16) DOT_(A4.y, 17) DOT_(A4.z, 18) DOT_(A4.w, 19)
            DOT_(A5.x, 20) DOT_(A5.y, 21) DOT_(A5.z, 22) DOT_(A5.w, 23)
            DOT_(a24, 24)
            #undef DOT_

            float e0 = __expf(l0), e1 = __expf(l1);
            float p0 = e0 * __builtin_amdgcn_rcpf(halfwave_sum(e0));
            float p1 = e1 * __builtin_amdgcn_rcpf(halfwave_sum(e1));

            const float* Wp = &Wb[(i * 32 + a) * WTS];
            const float4 W0 = ((const float4*)Wp)[0];
            const float4 W1 = ((const float4*)Wp)[1];
            const float4 W2 = ((const float4*)Wp)[2];
            const float4 W3 = ((const float4*)Wp)[3];

            float x0 = obs_s[r0 * HSTR + o], x1 = obs_s[r1 * HSTR + o];
            float ro0 = W3.w, ro1 = W3.w;
            // w1 = {W0.x..W0.w,W1.x}, b1 = {W1.y..W1.w,W2.x,W2.y},
            // w2 = {W2.z,W2.w,W3.x,W3.y,W3.z}, b2 = W3.w
            ro0 = fmaf(fmaxf(fmaf(x0, W0.x, W1.y), 0.f), W2.z, ro0);
            ro1 = fmaf(fmaxf(fmaf(x1, W0.x, W1.y), 0.f), W2.z, ro1);
            ro0 = fmaf(fmaxf(fmaf(x0, W0.y, W1.z), 0.f), W2.w, ro0);
            ro1 = fmaf(fmaxf(fmaf(x1, W0.y, W1.z), 0.f), W2.w, ro1);
            ro0 = fmaf(fmaxf(fmaf(x0, W0.z, W1.w), 0.f), W3.x, ro0);
            ro1 = fmaf(fmaxf(fmaf(x1, W0.z, W1.w), 0.f), W3.x, ro1);
            ro0 = fmaf(fmaxf(fmaf(x0, W0.w, W2.x), 0.f), W3.y, ro0);
            ro1 = fmaf(fmaxf(fmaf(x1, W0.w, W2.x), 0.f), W3.y, ro1);
            ro0 = fmaf(fmaxf(fmaf(x0, W1.x, W2.y), 0.f), W3.z, ro0);
            ro1 = fmaf(fmaxf(fmaf(x1, W1.x, W2.y), 0.f), W3.z, ro1);

            acc0 = fmaf(ro0, p0, acc0);
            acc1 = fmaf(ro1, p1, acc1);
        }

        if (c + 1 < NCH) stage_w(c + 1, (c + 1) & 1);  // v5 position: idle buffer
        asm volatile("s_waitcnt vmcnt(0)" ::: "memory"); // At DMA + W loads complete
        __syncthreads();
    }

    out[(row0 + r0) * TACT + a] = acc0;
    out[(row0 + r1) * TACT + a] = acc1;
}

extern "C" void kernel_launch(void* const* d_in, const int* in_sizes, int n_in,
                              void* d_out, int out_size, void* d_ws, size_t ws_size,
                              hipStream_t stream) {
    const float* obs = (const float*)d_in[0];
    const float* sw1 = (const float*)d_in[1];
    const float* sb1 = (const float*)d_in[2];
    const float* sw2 = (const float*)d_in[3];
    const float* sb2 = (const float*)d_in[4];
    const float* sw3 = (const float*)d_in[5];
    const float* sb3 = (const float*)d_in[6];
    const float* rw1 = (const float*)d_in[7];
    const float* rb1 = (const float*)d_in[8];
    const float* rw2 = (const float*)d_in[9];
    const float* rb2 = (const float*)d_in[10];
    const float* am  = (const float*)d_in[11];
    float* out = (float*)d_out;

    reflex_fused<<<TB / BT, 256, 0, stream>>>(obs, sw1, sb1, sw2, sb2, sw3, sb3,
                                              rw1, rb1, rw2, rb2, am, out);
}

// Round 10
// 57.970 us; speedup vs baseline: 1.4370x; 1.4370x over previous
//
#include <hip/hip_runtime.h>

// ReflexPolicy fused v10 = v5 protocol + conflict-free o-packed LDS layouts:
// At4[l][a] = float4 over 4 o's, W4[word][a] = float4 over 4 o's.
// Lane a reads consecutive 16B -> zero bank-conflict b128; 8-way ILP dot.

#define TOBS 64
#define TACT 32
#define TLAT 25
#define TB   8192
#define BT   16
#define NCH  16         // chunks of 4 o's
#define HSTR 68

#define DPP_ADD(x, ctrl) \
  ((x) + __builtin_bit_cast(float, __builtin_amdgcn_update_dpp( \
      0, __builtin_bit_cast(int, (x)), (ctrl), 0xF, 0xF, true)))

__device__ __forceinline__ float halfwave_sum(float x) {
    x = DPP_ADD(x, 0xB1);   // xor1
    x = DPP_ADD(x, 0x4E);   // xor2
    x = DPP_ADD(x, 0x141);  // row_half_mirror == xor4
    x = DPP_ADD(x, 0x140);  // row_mirror      == xor8
    int y = __builtin_amdgcn_ds_swizzle(__builtin_bit_cast(int, x), 0x401F); // xor16
    return x + __builtin_bit_cast(float, y);
}

__device__ __forceinline__ float sigmoidf_(float x) {
    return 1.0f / (1.0f + __expf(-x));
}

__global__ __launch_bounds__(256, 2)
void reflex_fused(const float* __restrict__ obs,
                  const float* __restrict__ sw1, const float* __restrict__ sb1,
                  const float* __restrict__ sw2, const float* __restrict__ sb2,
                  const float* __restrict__ sw3, const float* __restrict__ sb3,
                  const float* __restrict__ rw1, const float* __restrict__ rb1,
                  const float* __restrict__ rw2, const float* __restrict__ rb2,
                  const float* __restrict__ am,  float* __restrict__ out)
{
    __shared__ __align__(16) float obs_s[BT * HSTR];
    __shared__ __align__(16) float lat_s[BT * 26];
    __shared__ __align__(16) union {
        struct { float h1[BT * HSTR]; float h2[BT * HSTR]; } p1;
        struct { float4 At4[2][25 * 32]; float4 W4[2][16 * 32]; } p2;
    } U;

    const int tid  = threadIdx.x;
    const int row0 = blockIdx.x * BT;

    // ---------------- Phase 1: supervisor (weights from L2) ----------------
    {
        const int r = tid >> 4, f = tid & 15;
        *(float4*)&obs_s[r * HSTR + f * 4] =
            *(const float4*)&obs[(row0 + r) * TOBS + f * 4];
    }
    __syncthreads();

    {   // layer 1
        const int r = tid >> 4, j0 = (tid & 15) * 4;
        float4 acc = *(const float4*)&sb1[j0];
        #pragma unroll 8
        for (int k = 0; k < 64; ++k) {
            float x = obs_s[r * HSTR + k];
            const float4 w = *(const float4*)&sw1[k * 64 + j0];
            acc.x = fmaf(x, w.x, acc.x); acc.y = fmaf(x, w.y, acc.y);
            acc.z = fmaf(x, w.z, acc.z); acc.w = fmaf(x, w.w, acc.w);
        }
        *(float4*)&U.p1.h1[r * HSTR + j0] =
            make_float4(fmaxf(acc.x, 0.f), fmaxf(acc.y, 0.f),
                        fmaxf(acc.z, 0.f), fmaxf(acc.w, 0.f));
    }
    __syncthreads();

    {   // layer 2
        const int r = tid >> 4, j0 = (tid & 15) * 4;
        float4 acc = *(const float4*)&sb2[j0];
        #pragma unroll 8
        for (int k = 0; k < 64; ++k) {
            float x = U.p1.h1[r * HSTR + k];
            const float4 w = *(const float4*)&sw2[k * 64 + j0];
            acc.x = fmaf(x, w.x, acc.x); acc.y = fmaf(x, w.y, acc.y);
            acc.z = fmaf(x, w.z, acc.z); acc.w = fmaf(x, w.w, acc.w);
        }
        *(float4*)&U.p1.h2[r * HSTR + j0] =
            make_float4(fmaxf(acc.x, 0.f), fmaxf(acc.y, 0.f),
                        fmaxf(acc.z, 0.f), fmaxf(acc.w, 0.f));
    }
    __syncthreads();

    {   // layer 3 -> lat_s
        const int r = tid >> 4, q = tid & 15;
        if (q < 13) {
            const int j = q * 2;
            float a0 = sb3[j];
            float a1 = (j + 1 < TLAT) ? sb3[j + 1] : 0.f;
            #pragma unroll 8
            for (int k = 0; k < 64; ++k) {
                float x = U.p1.h2[r * HSTR + k];
                a0 = fmaf(x, sw3[k * TLAT + j], a0);
                if (j + 1 < TLAT) a1 = fmaf(x, sw3[k * TLAT + j + 1], a1);
            }
            lat_s[r * 26 + j] = sigmoidf_(a0);
            if (j + 1 < TLAT) lat_s[r * 26 + j + 1] = sigmoidf_(a1);
        }
    }
    __syncthreads();   // lat_s ready; h1/h2 (union) dead

    // ---------------- Phase 2 ----------------
    const int a  = tid & 31;
    const int hw = tid >> 5;
    const int r0 = hw * 2, r1 = r0 + 1;

    float latA[TLAT], latB[TLAT];
    #pragma unroll
    for (int l = 0; l < TLAT; ++l) {
        latA[l] = lat_s[r0 * 26 + l];
        latB[l] = lat_s[r1 * 26 + l];
    }

    // W word k source for reflex net n (= (c*4+o)*32 + a):
    auto wload = [&](int k, int n) -> float {
        if (k < 5)  return rw1[n * 5 + k];
        if (k < 10) return rb1[n * 5 + (k - 5)];
        if (k < 15) return rw2[n * 5 + (k - 10)];
        return rb2[n];
    };

    // Stage chunk c into buffer b. At4: 800 entries, W4: 512 entries; 256 threads.
    auto stage = [&](int c, int b) {
        const int cb = c * 128;
        {   // At entries tid, tid+256, tid+512 (+768 for tid<32)
            int e = tid, l = e >> 5, a_ = e & 31;
            const float* g = am + l * 2048 + cb + a_;
            float4 v; v.x = g[0]; v.y = g[32]; v.z = g[64]; v.w = g[96];
            U.p2.At4[b][e] = v;

            e = tid + 256; l = e >> 5; a_ = e & 31;
            const float* g2 = am + l * 2048 + cb + a_;
            float4 v2; v2.x = g2[0]; v2.y = g2[32]; v2.z = g2[64]; v2.w = g2[96];
            U.p2.At4[b][e] = v2;

            e = tid + 512; l = e >> 5; a_ = e & 31;
            const float* g3 = am + l * 2048 + cb + a_;
            float4 v3; v3.x = g3[0]; v3.y = g3[32]; v3.z = g3[64]; v3.w = g3[96];
            U.p2.At4[b][e] = v3;

            if (tid < 32) {
                e = tid + 768;                       // l = 24
                const float* g4 = am + 24 * 2048 + cb + tid;
                float4 v4; v4.x = g4[0]; v4.y = g4[32]; v4.z = g4[64]; v4.w = g4[96];
                U.p2.At4[b][e] = v4;
            }
        }
        {   // W entries tid (k 0..7), tid+256 (k 8..15)
            int k = tid >> 5, a_ = tid & 31;
            int n0 = cb + a_;
            float4 w;
            w.x = wload(k, n0);      w.y = wload(k, n0 + 32);
            w.z = wload(k, n0 + 64); w.w = wload(k, n0 + 96);
            U.p2.W4[b][tid] = w;

            k += 8;
            float4 w2;
            w2.x = wload(k, n0);      w2.y = wload(k, n0 + 32);
            w2.z = wload(k, n0 + 64); w2.w = wload(k, n0 + 96);
            U.p2.W4[b][tid + 256] = w2;
        }
    };

    float acc0 = 0.f, acc1 = 0.f;

    stage(0, 0);
    __syncthreads();

    for (int c = 0; c < NCH; ++c) {
        const float4* A4 = U.p2.At4[c & 1];
        const float4* Wb = U.p2.W4[c & 1];

        // ---- dot over l: 4 o's x 2 rows, 8 independent chains, 25 b128 reads
        float l00 = 0.f, l01 = 0.f, l02 = 0.f, l03 = 0.f;
        float l10 = 0.f, l11 = 0.f, l12 = 0.f, l13 = 0.f;
        #pragma unroll
        for (int l = 0; l < TLAT; ++l) {
            const float4 q = A4[l * 32 + a];
            l00 = fmaf(q.x, latA[l], l00); l10 = fmaf(q.x, latB[l], l10);
            l01 = fmaf(q.y, latA[l], l01); l11 = fmaf(q.y, latB[l], l11);
            l02 = fmaf(q.z, latA[l], l02); l12 = fmaf(q.z, latB[l], l12);
            l03 = fmaf(q.w, latA[l], l03); l13 = fmaf(q.w, latB[l], l13);
        }

        // ---- softmax over a (32-lane half-wave), 8 independent chains
        float e00 = __expf(l00), e01 = __expf(l01), e02 = __expf(l02), e03 = __expf(l03);
        float e10 = __expf(l10), e11 = __expf(l11), e12 = __expf(l12), e13 = __expf(l13);
        float p00 = e00 * __builtin_amdgcn_rcpf(halfwave_sum(e00));
        float p01 = e01 * __builtin_amdgcn_rcpf(halfwave_sum(e01));
        float p02 = e02 * __builtin_amdgcn_rcpf(halfwave_sum(e02));
        float p03 = e03 * __builtin_amdgcn_rcpf(halfwave_sum(e03));
        float p10 = e10 * __builtin_amdgcn_rcpf(halfwave_sum(e10));
        float p11 = e11 * __builtin_amdgcn_rcpf(halfwave_sum(e11));
        float p12 = e12 * __builtin_amdgcn_rcpf(halfwave_sum(e12));
        float p13 = e13 * __builtin_amdgcn_rcpf(halfwave_sum(e13));

        // ---- reflex MLPs: h-wise over 4 o's x 2 rows, 16 b128 W reads
        const int ob = c * 4;
        const float x00 = obs_s[r0 * HSTR + ob],     x10 = obs_s[r1 * HSTR + ob];
        const float x01 = obs_s[r0 * HSTR + ob + 1], x11 = obs_s[r1 * HSTR + ob + 1];
        const float x02 = obs_s[r0 * HSTR + ob + 2], x12 = obs_s[r1 * HSTR + ob + 2];
        const float x03 = obs_s[r0 * HSTR + ob + 3], x13 = obs_s[r1 * HSTR + ob + 3];

        const float4 B2 = Wb[15 * 32 + a];
        float q00 = B2.x, q01 = B2.y, q02 = B2.z, q03 = B2.w;
        float q10 = B2.x, q11 = B2.y, q12 = B2.z, q13 = B2.w;
        #pragma unroll
        for (int h = 0; h < 5; ++h) {
            const float4 w1v = Wb[h * 32 + a];
            const float4 b1v = Wb[(5 + h) * 32 + a];
            const float4 w2v = Wb[(10 + h) * 32 + a];
            q00 = fmaf(fmaxf(fmaf(x00, w1v.x, b1v.x), 0.f), w2v.x, q00);
            q10 = fmaf(fmaxf(fmaf(x10, w1v.x, b1v.x), 0.f), w2v.x, q10);
            q01 = fmaf(fmaxf(fmaf(x01, w1v.y, b1v.y), 0.f), w2v.y, q01);
            q11 = fmaf(fmaxf(fmaf(x11, w1v.y, b1v.y), 0.f), w2v.y, q11);
            q02 = fmaf(fmaxf(fmaf(x02, w1v.z, b1v.z), 0.f), w2v.z, q02);
            q12 = fmaf(fmaxf(fmaf(x12, w1v.z, b1v.z), 0.f), w2v.z, q12);
            q03 = fmaf(fmaxf(fmaf(x03, w1v.w, b1v.w), 0.f), w2v.w, q03);
            q13 = fmaf(fmaxf(fmaf(x13, w1v.w, b1v.w), 0.f), w2v.w, q13);
        }

        acc0 = fmaf(q00, p00, acc0); acc1 = fmaf(q10, p10, acc1);
        acc0 = fmaf(q01, p01, acc0); acc1 = fmaf(q11, p11, acc1);
        acc0 = fmaf(q02, p02, acc0); acc1 = fmaf(q12, p12, acc1);
        acc0 = fmaf(q03, p03, acc0); acc1 = fmaf(q13, p13, acc1);

        if (c + 1 < NCH) stage(c + 1, (c + 1) & 1);  // v5 protocol: stage after compute
        __syncthreads();
    }

    out[(row0 + r0) * TACT + a] = acc0;
    out[(row0 + r1) * TACT + a] = acc1;
}

extern "C" void kernel_launch(void* const* d_in, const int* in_sizes, int n_in,
                              void* d_out, int out_size, void* d_ws, size_t ws_size,
                              hipStream_t stream) {
    const float* obs = (const float*)d_in[0];
    const float* sw1 = (const float*)d_in[1];
    const float* sb1 = (const float*)d_in[2];
    const float* sw2 = (const float*)d_in[3];
    const float* sb2 = (const float*)d_in[4];
    const float* sw3 = (const float*)d_in[5];
    const float* sb3 = (const float*)d_in[6];
    const float* rw1 = (const float*)d_in[7];
    const float* rb1 = (const float*)d_in[8];
    const float* rw2 = (const float*)d_in[9];
    const float* rb2 = (const float*)d_in[10];
    const float* am  = (const float*)d_in[11];
    float* out = (float*)d_out;

    reflex_fused<<<TB / BT, 256, 0, stream>>>(obs, sw1, sb1, sw2, sb2, sw3, sb3,
                                              rw1, rb1, rw2, rb2, am, out);
}